// Round 15
// baseline (358.538 us; speedup 1.0000x reference)
//
#include <hip/hip_runtime.h>
#include <stdint.h>

typedef unsigned short u16;
typedef __attribute__((ext_vector_type(8))) short short8;
typedef __attribute__((ext_vector_type(4))) float f32x4;
typedef __attribute__((ext_vector_type(4))) u16 u16x4;
typedef __attribute__((ext_vector_type(4))) uint32_t u32x4;

#define NB 4
#define SEQ 2048
#define DM 1024
#define NH 16
#define DKh 64
#define DFF 4096
#define LOG2E 1.44269504089f

__device__ __forceinline__ u16 f2bf(float f) {
  union { float f; uint32_t u; } v; v.f = f;
  uint32_t u = v.u;
  return (u16)((u + 0x7FFFu + ((u >> 16) & 1u)) >> 16);
}

__device__ __forceinline__ uint32_t cvtpk(float lo, float hi) {
  uint32_t r;
  asm("v_cvt_pk_bf16_f32 %0, %1, %2" : "=v"(r) : "v"(lo), "v"(hi));
  return r;
}

__device__ __forceinline__ float fexp2(float x) {
  float r;
  asm("v_exp_f32 %0, %1" : "=v"(r) : "v"(x));
  return r;
}

__device__ __forceinline__ void gl16(const u16* g, u16* l) {
  __builtin_amdgcn_global_load_lds((const __attribute__((address_space(1))) void*)g,
                                   (__attribute__((address_space(3))) void*)l, 16, 0, 0);
}

// ---- merged prep: 6 weight transposes (fp32->bf16) + QKV bias concat, one launch ----
// blocks 0..4095: wq/wk/wv/wo (32x32 tiles); 4096..8191: w1; 8192..12287: w2; 12288..12299: bias_cat
__global__ __launch_bounds__(256) void prep(const float* __restrict__ wq, const float* __restrict__ wk,
                                            const float* __restrict__ wv, const float* __restrict__ wo,
                                            const float* __restrict__ w1, const float* __restrict__ w2,
                                            u16* __restrict__ wqT, u16* __restrict__ wkT,
                                            u16* __restrict__ wvT, u16* __restrict__ woT,
                                            u16* __restrict__ w1T, u16* __restrict__ w2T,
                                            const float* __restrict__ bq, const float* __restrict__ bk,
                                            const float* __restrict__ bv, float* __restrict__ bcat) {
  int idx = blockIdx.x;
  int tx = threadIdx.x, ty = threadIdx.y;
  if (idx >= 12288) {
    int i = (idx - 12288) * 256 + ty * 32 + tx;
    if (i < 3072) bcat[i] = (i < 1024) ? bq[i] : ((i < 2048) ? bk[i - 1024] : bv[i - 2048]);
    return;
  }
  const float* src; u16* dst; int R, C, bx, by;
  if (idx < 4096) {
    int z = idx >> 10;
    src = (z == 0) ? wq : (z == 1) ? wk : (z == 2) ? wv : wo;
    dst = (z == 0) ? wqT : (z == 1) ? wkT : (z == 2) ? wvT : woT;
    R = DM; C = DM; int i = idx & 1023; bx = i & 31; by = i >> 5;
  } else if (idx < 8192) {
    src = w1; dst = w1T; R = DM; C = DFF; int i = idx - 4096; bx = i & 127; by = i >> 7;
  } else {
    src = w2; dst = w2T; R = DFF; C = DM; int i = idx - 8192; bx = i & 31; by = i >> 5;
  }
  __shared__ float tile[32][33];
  int c0 = bx * 32, r0 = by * 32;
#pragma unroll
  for (int i = 0; i < 32; i += 8)
    tile[ty + i][tx] = src[(size_t)(r0 + ty + i) * C + c0 + tx];
  __syncthreads();
#pragma unroll
  for (int i = 0; i < 32; i += 8)
    dst[(size_t)(c0 + ty + i) * R + r0 + tx] = f2bf(tile[tx][ty + i]);
}

// ---- per-batch mask compaction: inverse map pinv[b][s] (-1 if masked), lengths, pad-bias ----
__global__ __launch_bounds__(1024) void compact_idx(const int* __restrict__ msk,
                                                    int* __restrict__ pinv,
                                                    int* __restrict__ lArr,
                                                    int* __restrict__ lpArr,
                                                    float* __restrict__ fbbc) {
  int b = blockIdx.x;
  int t = threadIdx.x;
  int lane = t & 63, w = t >> 6;
  int i0 = t * 2, i1 = t * 2 + 1;
  int m0 = msk[b * SEQ + i0] ? 1 : 0;
  int m1 = msk[b * SEQ + i1] ? 1 : 0;
  int s = m0 + m1;
  int run = s;
#pragma unroll
  for (int d = 1; d < 64; d <<= 1) {
    int v = __shfl_up(run, d);
    if (lane >= d) run += v;
  }
  __shared__ int wtot[16];
  __shared__ int woff[17];
  if (lane == 63) wtot[w] = run;
  __syncthreads();
  if (t == 0) {
    int acc = 0;
#pragma unroll
    for (int i = 0; i < 16; ++i) { woff[i] = acc; acc += wtot[i]; }
    woff[16] = acc;
  }
  __syncthreads();
  int excl = run - s + woff[w];
  pinv[b * SEQ + i0] = m0 ? excl : -1;
  pinv[b * SEQ + i1] = m1 ? (excl + m0) : -1;
  int L = woff[16];
  if (t == 0) {
    lArr[b] = L;
    int LP = (L + 63) & ~63;
    if (LP == 0) LP = 64;
    lpArr[b] = LP;
  }
  for (int l = t; l < SEQ; l += 1024)
    fbbc[b * SEQ + l] = (l < L) ? 0.0f : -1e9f;
}

// ---- custom LayerNorm (scalar alpha/beta, unbiased std, eps on std) -> bf16 ----
__global__ __launch_bounds__(256) void ln_bf16(const float* __restrict__ x,
                                               u16* __restrict__ out,
                                               const float* __restrict__ alpha,
                                               const float* __restrict__ beta) {
  int row = blockIdx.x;
  const float4* xr = (const float4*)(x + (size_t)row * DM);
  int t = threadIdx.x;
  float4 v = xr[t];
  float s = v.x + v.y + v.z + v.w;
  float s2 = v.x * v.x + v.y * v.y + v.z * v.z + v.w * v.w;
#pragma unroll
  for (int m = 1; m < 64; m <<= 1) { s += __shfl_xor(s, m); s2 += __shfl_xor(s2, m); }
  __shared__ float red[8];
  int wid = t >> 6, lane = t & 63;
  if (lane == 0) { red[wid] = s; red[wid + 4] = s2; }
  __syncthreads();
  float S = red[0] + red[1] + red[2] + red[3];
  float S2 = red[4] + red[5] + red[6] + red[7];
  float mean = S * (1.0f / DM);
  float var = fmaxf((S2 - S * mean) * (1.0f / (DM - 1)), 0.0f);
  float inv = alpha[0] / (sqrtf(var) + 1e-6f);
  float bet = beta[0];
  u16x4 o;
  o[0] = f2bf((v.x - mean) * inv + bet);
  o[1] = f2bf((v.y - mean) * inv + bet);
  o[2] = f2bf((v.z - mean) * inv + bet);
  o[3] = f2bf((v.w - mean) * inv + bet);
  *(u16x4*)(out + (size_t)row * DM + t * 4) = o;
}

// ======== 256x128-tile pipelined GEMM: BK=64, 3-deep LDS ring (144KB), counted vmcnt ========
// 512 thr = 8 waves (4M x 2N), per-wave 64x64, 32 MFMA per K-tile per wave.
// Halves barrier/wait cadence vs BK=32 (same proven 3-ring schedule); 1 block/CU
// (FFN2/O-proj measured 900 TF at 1 block/CU, so occupancy is not the limiter).
// MODE 0: fused QKV epilogue; MODE 2: fp32 resid+acc+bias; MODE 3: bf16 relu.
template <int MODE>
__global__ __launch_bounds__(512, 2) void gemm_v2(const u16* __restrict__ A,
                                                  const u16* __restrict__ WT,
                                                  const float* __restrict__ bias,
                                                  const float* __restrict__ resid,
                                                  void* __restrict__ outp,
                                                  const int* __restrict__ pinv,
                                                  int M, int N, int K, float qscale) {
  extern __shared__ u16 lds[];
  int tid = threadIdx.x;
  int lane = tid & 63, wid = tid >> 6;
  int lr = lane & 15, lg = lane >> 4;
  int wr = wid >> 1, wc = wid & 1;
  int nbx = N >> 7;
  int nwg = (M >> 8) * nbx;
  int lid = blockIdx.x;
  int swz = (lid & 7) * (nwg >> 3) + (lid >> 3);
  int m0 = (swz / nbx) << 8, n0 = (swz % nbx) << 7;

  // staging: sweep = 64 rows x 64 cols (4096 u16); A = 4 sweeps, B = 2 sweeps.
  // LDS linear dest (tid*8); source chunk pre-swizzled: chunk ^ (row&7).
  int sr2 = tid >> 3;                 // 0..63 row within sweep
  int sch2 = tid & 7;
  int csrc8 = (sch2 ^ (sr2 & 7)) * 8;
  size_t a_src = (size_t)(m0 + sr2) * K + csrc8;
  size_t b_src = (size_t)(n0 + sr2) * K + csrc8;
  u16* dstb = lds + tid * 8;

#define STAGE(B_, T_) do { \
    const u16* as_ = A + a_src + (size_t)(T_) * 64; \
    gl16(as_,                   dstb + (B_) * 24576); \
    gl16(as_ + (size_t)64 * K,  dstb + (B_) * 24576 + 4096); \
    gl16(as_ + (size_t)128 * K, dstb + (B_) * 24576 + 8192); \
    gl16(as_ + (size_t)192 * K, dstb + (B_) * 24576 + 12288); \
    const u16* bs_ = WT + b_src + (size_t)(T_) * 64; \
    gl16(bs_,                   dstb + (B_) * 24576 + 16384); \
    gl16(bs_ + (size_t)64 * K,  dstb + (B_) * 24576 + 20480); \
  } while (0)

  // fragment reads: row stride 64; chunk = ((kk*4+lg) ^ (lr&7)) * 8
  int xo8 = lr & 7;
  int ckk[2] = {((0 + lg) ^ xo8) * 8, ((4 + lg) ^ xo8) * 8};
  int offA[4], offB[4];
#pragma unroll
  for (int i = 0; i < 4; ++i) offA[i] = (wr * 64 + i * 16 + lr) * 64;
#pragma unroll
  for (int j = 0; j < 4; ++j) offB[j] = 16384 + (wc * 64 + j * 16 + lr) * 64;

  f32x4 acc[4][4] = {};

  int NT = K >> 6;
  STAGE(0, 0);
  STAGE(1, 1);
  asm volatile("s_waitcnt vmcnt(6)" ::: "memory");
  __builtin_amdgcn_s_barrier();

  int buf = 0;
  for (int t = 0; t < NT; ++t) {
    const u16* la = lds + buf * 24576;
    int b2 = buf - 1; if (b2 < 0) b2 += 3;
    short8 af[4][2], bfr[4][2];
#pragma unroll
    for (int i = 0; i < 4; ++i) {
      af[i][0] = *(const short8*)&la[offA[i] + ckk[0]];
      af[i][1] = *(const short8*)&la[offA[i] + ckk[1]];
    }
#pragma unroll
    for (int j = 0; j < 4; ++j) {
      bfr[j][0] = *(const short8*)&la[offB[j] + ckk[0]];
      bfr[j][1] = *(const short8*)&la[offB[j] + ckk[1]];
    }
    if (t + 2 < NT) STAGE(b2, t + 2);
    __builtin_amdgcn_s_setprio(1);
#pragma unroll
    for (int kk = 0; kk < 2; ++kk)
#pragma unroll
      for (int i = 0; i < 4; ++i)
#pragma unroll
        for (int j = 0; j < 4; ++j)
          acc[i][j] = __builtin_amdgcn_mfma_f32_16x16x32_bf16(af[i][kk], bfr[j][kk], acc[i][j], 0, 0, 0);
    __builtin_amdgcn_s_setprio(0);
    if (t < NT - 2) asm volatile("s_waitcnt vmcnt(6)" ::: "memory");
    else            asm volatile("s_waitcnt vmcnt(0)" ::: "memory");
    __builtin_amdgcn_s_barrier();
    __builtin_amdgcn_sched_barrier(0);
    buf = (buf == 2) ? 0 : buf + 1;
  }
#undef STAGE

#pragma unroll
  for (int i = 0; i < 4; ++i) {
#pragma unroll
    for (int j = 0; j < 4; ++j) {
      int col = n0 + wc * 64 + j * 16 + lr;
      float bi = bias[col];
      int rbase = m0 + wr * 64 + i * 16 + lg * 4;
      if (MODE == 2) {
        float* o = (float*)outp;
#pragma unroll
        for (int r = 0; r < 4; ++r) {
          size_t idx = (size_t)(rbase + r) * N + col;
          o[idx] = resid[idx] + acc[i][j][r] + bi;
        }
      } else if (MODE == 3) {
        u16* o = (u16*)outp;
#pragma unroll
        for (int r = 0; r < 4; ++r)
          o[(size_t)(rbase + r) * N + col] = f2bf(fmaxf(acc[i][j][r] + bi, 0.0f));
      } else {
        u16* qb = (u16*)outp;
        int which = col >> 10, nc = col & 1023;
        int hh = nc >> 6, dd = nc & 63;
        int bb = rbase >> 11, ss = rbase & 2047;
        if (which == 0) {
#pragma unroll
          for (int r = 0; r < 4; ++r)
            qb[((size_t)(bb * NH + hh) * SEQ + (ss + r)) * DKh + dd] = f2bf((acc[i][j][r] + bi) * qscale);
        } else {
          int4 p4 = *(const int4*)(pinv + bb * SEQ + ss);
          int pos[4] = {p4.x, p4.y, p4.z, p4.w};
          if (which == 1) {
            u16* kcb = qb + (size_t)(8u << 20);
#pragma unroll
            for (int r = 0; r < 4; ++r)
              if (pos[r] >= 0)
                kcb[((size_t)(bb * NH + hh) * SEQ + pos[r]) * DKh + dd] = f2bf(acc[i][j][r] + bi);
          } else {
            u16* vcb = qb + (size_t)2 * (8u << 20);
#pragma unroll
            for (int r = 0; r < 4; ++r)
              if (pos[r] >= 0) {
                int l = pos[r];
                int lo = l & 63;
                int pi = ((lo >> 4) & 1) * 32 + ((lo >> 2) & 3) * 8 + (lo >> 5) * 4 + (lo & 3);
                vcb[((size_t)(bb * NH + hh) * DKh + dd) * SEQ + (l & ~63) + pi] = f2bf(acc[i][j][r] + bi);
              }
          }
        }
      }
    }
  }
}

// ---- flash attention over COMPACTED kv: 512 thr (8 waves x 32 q-rows), KVBLK=128,
// gl16-staged double-buffer with COUNTED vmcnt (loads stay in flight across barriers).
__global__ __launch_bounds__(512) void attn_fwd(const u16* __restrict__ q,
                                                const u16* __restrict__ kc,
                                                const u16* __restrict__ vc,
                                                const int* __restrict__ lArr,
                                                const int* __restrict__ lpArr,
                                                const float* __restrict__ fbbc,
                                                u16* __restrict__ ctx) {
  __shared__ u16 lds[2][16384];
  int tid = threadIdx.x;
  int wid = tid >> 6, lane = tid & 63;
  int lr = lane & 15, lg = lane >> 4;
  int bh = blockIdx.x;
  int b = bh >> 4, hh = bh & 15;
  int q0 = blockIdx.y * 256 + wid * 32;
  const u16* qbase = q + (size_t)bh * SEQ * DKh;
  const u16* kcb = kc + (size_t)bh * SEQ * DKh;
  const u16* vcb = vc + (size_t)bh * DKh * SEQ;
  const float* fbbase = fbbc + b * SEQ;
  int Lb = lArr[b];
  int LP = lpArr[b];

  short8 qf[2][2];
#pragma unroll
  for (int i = 0; i < 2; ++i)
#pragma unroll
    for (int kk = 0; kk < 2; ++kk)
      qf[i][kk] = *(const short8*)(qbase + (size_t)(q0 + i * 16 + lr) * DKh + kk * 32 + lg * 8);

  int srow = tid >> 3;
  int schk = tid & 7;
  int ks0 = srow * 64 + ((schk ^ (srow & 7)) * 8);
  int vs0 = srow * SEQ + ((schk ^ (srow & 7)) * 8);
  int dst0 = tid * 8;

#define STAGE(B_, KV0) do { \
    gl16(kcb + (size_t)(KV0) * 64 + ks0, &lds[B_][dst0]); \
    gl16(kcb + (size_t)((KV0) + 64) * 64 + ks0, &lds[B_][dst0 + 4096]); \
    gl16(vcb + (size_t)(KV0) + vs0, &lds[B_][dst0 + 8192]); \
    gl16(vcb + (size_t)(KV0) + 64 + vs0, &lds[B_][dst0 + 12288]); \
  } while (0)

  int swzc = (lr & 7) << 3;

  f32x4 ot[2][4] = {};
  float mrow[2] = {-3e38f, -3e38f};
  float lsum[2] = {0.0f, 0.0f};

  STAGE(0, 0);
  asm volatile("s_waitcnt vmcnt(0)" ::: "memory");
  __builtin_amdgcn_s_barrier();

  int buf = 0;
  for (int kv0 = 0; kv0 < LP; kv0 += 128) {
    bool more = (kv0 + 128 < LP);
    if (more) STAGE(buf ^ 1, kv0 + 128);
    if (more) asm volatile("s_waitcnt vmcnt(4)" ::: "memory");
    else      asm volatile("s_waitcnt vmcnt(0)" ::: "memory");
    __builtin_amdgcn_s_barrier();

#pragma unroll
    for (int sB = 0; sB < 2; ++sB) {
      const u16* Ks = &lds[buf][sB * 4096];
      const u16* Vs = &lds[buf][8192 + sB * 4096];
      int kvs = kv0 + sB * 64;

      f32x4 st[2][4] = {};
      __builtin_amdgcn_s_setprio(1);
#pragma unroll
      for (int kk = 0; kk < 2; ++kk) {
        short8 kf[4];
#pragma unroll
        for (int j = 0; j < 4; ++j)
          kf[j] = *(const short8*)&Ks[(j * 16 + lr) * 64 + ((kk * 32 + lg * 8) ^ swzc)];
#pragma unroll
        for (int i = 0; i < 2; ++i)
#pragma unroll
          for (int j = 0; j < 4; ++j)
            st[i][j] = __builtin_amdgcn_mfma_f32_16x16x32_bf16(kf[j], qf[i][kk], st[i][j], 0, 0, 0);
      }
      __builtin_amdgcn_s_setprio(0);

      bool tail = (kvs + 64 > Lb);

      u32x4 pa[2][2];
#pragma unroll
      for (int i = 0; i < 2; ++i) {
        float p[4][4];
        if (tail) {
#pragma unroll
          for (int j = 0; j < 4; ++j) {
            float4 f4 = *(const float4*)(fbbase + kvs + j * 16 + lg * 4);
            p[j][0] = st[i][j][0] + f4.x;
            p[j][1] = st[i][j][1] + f4.y;
            p[j][2] = st[i][j][2] + f4.z;
            p[j][3] = st[i][j][3] + f4.w;
          }
        } else {
#pragma unroll
          for (int j = 0; j < 4; ++j)
#pragma unroll
            for (int r = 0; r < 4; ++r) p[j][r] = st[i][j][r];
        }
        float mx = -3e38f;
#pragma unroll
        for (int j = 0; j < 4; ++j)
#pragma unroll
          for (int r = 0; r < 4; ++r) mx = fmaxf(mx, p[j][r]);
        mx = fmaxf(mx, __shfl_xor(mx, 16));
        mx = fmaxf(mx, __shfl_xor(mx, 32));
        float mnew = fmaxf(mrow[i], mx);
        if (!__all(mnew - mrow[i] <= 8.0f)) {
          float corr = fexp2(mrow[i] - mnew);
          lsum[i] *= corr;
#pragma unroll
          for (int jd = 0; jd < 4; ++jd)
#pragma unroll
            for (int r = 0; r < 4; ++r) ot[i][jd][r] *= corr;
          mrow[i] = mnew;
        }
        float ps = 0.0f;
#pragma unroll
        for (int j = 0; j < 4; ++j)
#pragma unroll
          for (int r = 0; r < 4; ++r) {
            float pv = fexp2(p[j][r] - mrow[i]);
            p[j][r] = pv;
            ps += pv;
          }
        ps += __shfl_xor(ps, 16);
        ps += __shfl_xor(ps, 32);
        lsum[i] += ps;
#pragma unroll
        for (int ks = 0; ks < 2; ++ks) {
          pa[i][ks][0] = cvtpk(p[ks][0], p[ks][1]);
          pa[i][ks][1] = cvtpk(p[ks][2], p[ks][3]);
          pa[i][ks][2] = cvtpk(p[ks + 2][0], p[ks + 2][1]);
          pa[i][ks][3] = cvtpk(p[ks + 2][2], p[ks + 2][3]);
        }
      }

      __builtin_amdgcn_s_setprio(1);
#pragma unroll
      for (int ks = 0; ks < 2; ++ks) {
        short8 vf[4];
#pragma unroll
        for (int jd = 0; jd < 4; ++jd)
          vf[jd] = *(const short8*)&Vs[(jd * 16 + lr) * 64 + ((ks * 32 + lg * 8) ^ swzc)];
#pragma unroll
        for (int i = 0; i < 2; ++i)
#pragma unroll
          for (int jd = 0; jd < 4; ++jd)
            ot[i][jd] = __builtin_amdgcn_mfma_f32_16x16x32_bf16(vf[jd], *(short8*)&pa[i][ks], ot[i][jd], 0, 0, 0);
      }
      __builtin_amdgcn_s_setprio(0);
    }
    __builtin_amdgcn_s_barrier();
    buf ^= 1;
  }
#undef STAGE

  asm volatile("s_waitcnt vmcnt(0)" ::: "memory");
  __builtin_amdgcn_s_barrier();

  float inv0 = 1.0f / lsum[0], inv1 = 1.0f / lsum[1];
  u16* ep = &lds[0][wid * 2048];
#pragma unroll
  for (int i = 0; i < 2; ++i) {
    float inv = i ? inv1 : inv0;
#pragma unroll
    for (int jd = 0; jd < 4; ++jd) {
      uint32_t w0 = cvtpk(ot[i][jd][0] * inv, ot[i][jd][1] * inv);
      uint32_t w1 = cvtpk(ot[i][jd][2] * inv, ot[i][jd][3] * inv);
      uint32_t pk2[2] = {w0, w1};
      *(u16x4*)&ep[(i * 16 + lr) * 64 + ((jd * 16 + lg * 4) ^ swzc)] = *(u16x4*)pk2;
    }
  }
  __syncthreads();
  int q_ = lane >> 1;
  size_t orow = ((size_t)b * SEQ + q0 + q_) * DM + hh * DKh;
#pragma unroll
  for (int it = 0; it < 4; ++it) {
    int dc = (lane & 1) * 32 + it * 8;
    short8 vv = *(const short8*)&ep[q_ * 64 + (dc ^ ((q_ & 7) << 3))];
    *(short8*)(ctx + orow + dc) = vv;
  }
}

extern "C" void kernel_launch(void* const* d_in, const int* in_sizes, int n_in,
                              void* d_out, int out_size, void* d_ws, size_t ws_size,
                              hipStream_t stream) {
  const float* x   = (const float*)d_in[0];
  const int*   msk = (const int*)d_in[1];
  const float* wq  = (const float*)d_in[2];
  const float* bq  = (const float*)d_in[3];
  const float* wk  = (const float*)d_in[4];
  const float* bk  = (const float*)d_in[5];
  const float* wv  = (const float*)d_in[6];
  const float* bv  = (const float*)d_in[7];
  const float* wo  = (const float*)d_in[8];
  const float* bo  = (const float*)d_in[9];
  const float* w1  = (const float*)d_in[10];
  const float* b1  = (const float*)d_in[11];
  const float* w2  = (const float*)d_in[12];
  const float* b2  = (const float*)d_in[13];
  const float* a1  = (const float*)d_in[14];
  const float* be1 = (const float*)d_in[15];
  const float* a2  = (const float*)d_in[16];
  const float* be2 = (const float*)d_in[17];
  float* out = (float*)d_out;

  u16* wqT = (u16*)d_ws;
  u16* wkT = wqT + (1u << 20);
  u16* wvT = wkT + (1u << 20);
  u16* woT = wvT + (1u << 20);
  u16* w1T = woT + (1u << 20);
  u16* w2T = w1T + (4u << 20);
  u16* xn  = w2T + (4u << 20);
  u16* qb  = xn  + (8u << 20);
  u16* kb  = qb  + (8u << 20);     // compacted K [bh][l][64]
  u16* vtb = kb  + (8u << 20);     // compacted+permuted V^T [bh][d][*]
  u16* ctx = vtb + (8u << 20);
  u16* hb  = qb;                   // FFN hidden reuses qb..ctx (64 MB)
  float* bcat = (float*)ctx;       // QKV fused bias; ctx not live until attn
  int*   pinv = (int*)(ctx + (8u << 20));
  int*   lArr = pinv + NB * SEQ;
  int*   lpArr = lArr + 16;
  float* fbbc = (float*)(lpArr + 16);

  (void)hipFuncSetAttribute((const void*)gemm_v2<0>, hipFuncAttributeMaxDynamicSharedMemorySize, 144 * 1024);
  (void)hipFuncSetAttribute((const void*)gemm_v2<2>, hipFuncAttributeMaxDynamicSharedMemorySize, 144 * 1024);
  (void)hipFuncSetAttribute((const void*)gemm_v2<3>, hipFuncAttributeMaxDynamicSharedMemorySize, 144 * 1024);

  dim3 tb(32, 8);
  prep<<<12300, tb, 0, stream>>>(wq, wk, wv, wo, w1, w2, wqT, wkT, wvT, woT, w1T, w2T, bq, bk, bv, bcat);
  compact_idx<<<NB, 1024, 0, stream>>>(msk, pinv, lArr, lpArr, fbbc);

  ln_bf16<<<NB * SEQ, 256, 0, stream>>>(x, xn, a1, be1);

  // fused QKV: N=3072, 256x128 tiles -> grid 768
  gemm_v2<0><<<768, 512, 144 * 1024, stream>>>(xn, wqT, bcat, nullptr, qb, pinv, NB * SEQ, 3 * DM, DM, 0.125f * LOG2E);

  attn_fwd<<<dim3(NB * NH, SEQ / 256), 512, 0, stream>>>(qb, kb, vtb, lArr, lpArr, fbbc, ctx);

  // O-proj + residual: grid 256
  gemm_v2<2><<<256, 512, 144 * 1024, stream>>>(ctx, woT, bo, x, out, nullptr, NB * SEQ, DM, DM, 1.0f);

  ln_bf16<<<NB * SEQ, 256, 0, stream>>>(out, xn, a2, be2);

  // FFN1: N=4096 -> grid 1024
  gemm_v2<3><<<1024, 512, 144 * 1024, stream>>>(xn, w1T, b1, nullptr, hb, nullptr, NB * SEQ, DFF, DM, 1.0f);

  // FFN2 + residual: K=4096, grid 256
  gemm_v2<2><<<256, 512, 144 * 1024, stream>>>(hb, w2T, b2, out, out, nullptr, NB * SEQ, DM, DFF, 1.0f);
}

// Round 16
// 343.557 us; speedup vs baseline: 1.0436x; 1.0436x over previous
//
#include <hip/hip_runtime.h>
#include <stdint.h>

typedef unsigned short u16;
typedef __attribute__((ext_vector_type(8))) short short8;
typedef __attribute__((ext_vector_type(4))) float f32x4;
typedef __attribute__((ext_vector_type(4))) u16 u16x4;
typedef __attribute__((ext_vector_type(4))) uint32_t u32x4;

#define NB 4
#define SEQ 2048
#define DM 1024
#define NH 16
#define DKh 64
#define DFF 4096
#define LOG2E 1.44269504089f

__device__ __forceinline__ u16 f2bf(float f) {
  union { float f; uint32_t u; } v; v.f = f;
  uint32_t u = v.u;
  return (u16)((u + 0x7FFFu + ((u >> 16) & 1u)) >> 16);
}

__device__ __forceinline__ uint32_t cvtpk(float lo, float hi) {
  uint32_t r;
  asm("v_cvt_pk_bf16_f32 %0, %1, %2" : "=v"(r) : "v"(lo), "v"(hi));
  return r;
}

__device__ __forceinline__ float fexp2(float x) {
  float r;
  asm("v_exp_f32 %0, %1" : "=v"(r) : "v"(x));
  return r;
}

__device__ __forceinline__ void gl16(const u16* g, u16* l) {
  __builtin_amdgcn_global_load_lds((const __attribute__((address_space(1))) void*)g,
                                   (__attribute__((address_space(3))) void*)l, 16, 0, 0);
}

// ---- merged prep: 6 weight transposes (fp32->bf16) + QKV bias concat, one launch ----
__global__ __launch_bounds__(256) void prep(const float* __restrict__ wq, const float* __restrict__ wk,
                                            const float* __restrict__ wv, const float* __restrict__ wo,
                                            const float* __restrict__ w1, const float* __restrict__ w2,
                                            u16* __restrict__ wqT, u16* __restrict__ wkT,
                                            u16* __restrict__ wvT, u16* __restrict__ woT,
                                            u16* __restrict__ w1T, u16* __restrict__ w2T,
                                            const float* __restrict__ bq, const float* __restrict__ bk,
                                            const float* __restrict__ bv, float* __restrict__ bcat) {
  int idx = blockIdx.x;
  int tx = threadIdx.x, ty = threadIdx.y;
  if (idx >= 12288) {
    int i = (idx - 12288) * 256 + ty * 32 + tx;
    if (i < 3072) bcat[i] = (i < 1024) ? bq[i] : ((i < 2048) ? bk[i - 1024] : bv[i - 2048]);
    return;
  }
  const float* src; u16* dst; int R, C, bx, by;
  if (idx < 4096) {
    int z = idx >> 10;
    src = (z == 0) ? wq : (z == 1) ? wk : (z == 2) ? wv : wo;
    dst = (z == 0) ? wqT : (z == 1) ? wkT : (z == 2) ? wvT : woT;
    R = DM; C = DM; int i = idx & 1023; bx = i & 31; by = i >> 5;
  } else if (idx < 8192) {
    src = w1; dst = w1T; R = DM; C = DFF; int i = idx - 4096; bx = i & 127; by = i >> 7;
  } else {
    src = w2; dst = w2T; R = DFF; C = DM; int i = idx - 8192; bx = i & 31; by = i >> 5;
  }
  __shared__ float tile[32][33];
  int c0 = bx * 32, r0 = by * 32;
#pragma unroll
  for (int i = 0; i < 32; i += 8)
    tile[ty + i][tx] = src[(size_t)(r0 + ty + i) * C + c0 + tx];
  __syncthreads();
#pragma unroll
  for (int i = 0; i < 32; i += 8)
    dst[(size_t)(c0 + ty + i) * R + r0 + tx] = f2bf(tile[tx][ty + i]);
}

// ---- per-batch mask compaction: inverse map pinv[b][s] (-1 if masked), lengths, pad-bias ----
__global__ __launch_bounds__(1024) void compact_idx(const int* __restrict__ msk,
                                                    int* __restrict__ pinv,
                                                    int* __restrict__ lArr,
                                                    int* __restrict__ lpArr,
                                                    float* __restrict__ fbbc) {
  int b = blockIdx.x;
  int t = threadIdx.x;
  int lane = t & 63, w = t >> 6;
  int i0 = t * 2, i1 = t * 2 + 1;
  int m0 = msk[b * SEQ + i0] ? 1 : 0;
  int m1 = msk[b * SEQ + i1] ? 1 : 0;
  int s = m0 + m1;
  int run = s;
#pragma unroll
  for (int d = 1; d < 64; d <<= 1) {
    int v = __shfl_up(run, d);
    if (lane >= d) run += v;
  }
  __shared__ int wtot[16];
  __shared__ int woff[17];
  if (lane == 63) wtot[w] = run;
  __syncthreads();
  if (t == 0) {
    int acc = 0;
#pragma unroll
    for (int i = 0; i < 16; ++i) { woff[i] = acc; acc += wtot[i]; }
    woff[16] = acc;
  }
  __syncthreads();
  int excl = run - s + woff[w];
  pinv[b * SEQ + i0] = m0 ? excl : -1;
  pinv[b * SEQ + i1] = m1 ? (excl + m0) : -1;
  int L = woff[16];
  if (t == 0) {
    lArr[b] = L;
    int LP = (L + 63) & ~63;
    if (LP == 0) LP = 64;
    lpArr[b] = LP;
  }
  for (int l = t; l < SEQ; l += 1024)
    fbbc[b * SEQ + l] = (l < L) ? 0.0f : -1e9f;
}

// ---- custom LayerNorm (scalar alpha/beta, unbiased std, eps on std) -> bf16 ----
__global__ __launch_bounds__(256) void ln_bf16(const float* __restrict__ x,
                                               u16* __restrict__ out,
                                               const float* __restrict__ alpha,
                                               const float* __restrict__ beta) {
  int row = blockIdx.x;
  const float4* xr = (const float4*)(x + (size_t)row * DM);
  int t = threadIdx.x;
  float4 v = xr[t];
  float s = v.x + v.y + v.z + v.w;
  float s2 = v.x * v.x + v.y * v.y + v.z * v.z + v.w * v.w;
#pragma unroll
  for (int m = 1; m < 64; m <<= 1) { s += __shfl_xor(s, m); s2 += __shfl_xor(s2, m); }
  __shared__ float red[8];
  int wid = t >> 6, lane = t & 63;
  if (lane == 0) { red[wid] = s; red[wid + 4] = s2; }
  __syncthreads();
  float S = red[0] + red[1] + red[2] + red[3];
  float S2 = red[4] + red[5] + red[6] + red[7];
  float mean = S * (1.0f / DM);
  float var = fmaxf((S2 - S * mean) * (1.0f / (DM - 1)), 0.0f);
  float inv = alpha[0] / (sqrtf(var) + 1e-6f);
  float bet = beta[0];
  u16x4 o;
  o[0] = f2bf((v.x - mean) * inv + bet);
  o[1] = f2bf((v.y - mean) * inv + bet);
  o[2] = f2bf((v.z - mean) * inv + bet);
  o[3] = f2bf((v.w - mean) * inv + bet);
  *(u16x4*)(out + (size_t)row * DM + t * 4) = o;
}

// ======== 256x128-tile pipelined GEMM (BK=32, 3-deep LDS ring 72KB, 2 blocks/CU) ========
// Best-measured configuration (r12/r14: 900 TF). BK=64 (r15), 2-buf (r13), and
// 8-phase (r9/r10) all regressed — this 3-ring + counted vmcnt(3) is the local optimum.
// MODE 0: fused QKV epilogue; MODE 2: fp32 resid+acc+bias; MODE 3: bf16 relu.
template <int MODE>
__global__ __launch_bounds__(512, 4) void gemm_v2(const u16* __restrict__ A,
                                                  const u16* __restrict__ WT,
                                                  const float* __restrict__ bias,
                                                  const float* __restrict__ resid,
                                                  void* __restrict__ outp,
                                                  const int* __restrict__ pinv,
                                                  int M, int N, int K, float qscale) {
  extern __shared__ u16 lds[];
  int tid = threadIdx.x;
  int lane = tid & 63, wid = tid >> 6;
  int lr = lane & 15, lg = lane >> 4;
  int wr = wid >> 1, wc = wid & 1;
  int nbx = N >> 7;
  int nwg = (M >> 8) * nbx;
  int lid = blockIdx.x;
  int swz = (lid & 7) * (nwg >> 3) + (lid >> 3);
  int m0 = (swz / nbx) << 8, n0 = (swz % nbx) << 7;

  int sr = tid >> 2;
  int sch = tid & 3;
  int scs = sch ^ ((sr >> 1) & 3);
  size_t a_src = (size_t)(m0 + sr) * K + scs * 8;
  size_t b_src = (size_t)(n0 + sr) * K + scs * 8;
  u16* a_dst = lds + sr * 32 + sch * 8;
  u16* b_dst = lds + 8192 + sr * 32 + sch * 8;

#define STAGE(B_, T_) do { \
    gl16(A + a_src + (size_t)(T_) * 32, a_dst + (B_) * 12288); \
    gl16(A + a_src + (size_t)128 * K + (size_t)(T_) * 32, a_dst + (B_) * 12288 + 4096); \
    gl16(WT + b_src + (size_t)(T_) * 32, b_dst + (B_) * 12288); \
  } while (0)

  int rchunk = (lg ^ ((lr >> 1) & 3)) * 8;
  int offA[4], offB[4];
#pragma unroll
  for (int i = 0; i < 4; ++i) offA[i] = (wr * 64 + i * 16 + lr) * 32 + rchunk;
#pragma unroll
  for (int j = 0; j < 4; ++j) offB[j] = 8192 + (wc * 64 + j * 16 + lr) * 32 + rchunk;

  f32x4 acc[4][4] = {};

  int NT = K >> 5;
  STAGE(0, 0);
  STAGE(1, 1);
  asm volatile("s_waitcnt vmcnt(3)" ::: "memory");
  __builtin_amdgcn_s_barrier();

  int buf = 0;
  for (int t = 0; t < NT; ++t) {
    const u16* la = lds + buf * 12288;
    int b2 = buf - 1; if (b2 < 0) b2 += 3;
    short8 af[4], bfr[4];
#pragma unroll
    for (int i = 0; i < 4; ++i) af[i] = *(const short8*)&la[offA[i]];
#pragma unroll
    for (int j = 0; j < 4; ++j) bfr[j] = *(const short8*)&la[offB[j]];
    if (t + 2 < NT) STAGE(b2, t + 2);
    __builtin_amdgcn_s_setprio(1);
#pragma unroll
    for (int i = 0; i < 4; ++i)
#pragma unroll
      for (int j = 0; j < 4; ++j)
        acc[i][j] = __builtin_amdgcn_mfma_f32_16x16x32_bf16(af[i], bfr[j], acc[i][j], 0, 0, 0);
    __builtin_amdgcn_s_setprio(0);
    if (t < NT - 2) asm volatile("s_waitcnt vmcnt(3)" ::: "memory");
    else            asm volatile("s_waitcnt vmcnt(0)" ::: "memory");
    __builtin_amdgcn_s_barrier();
    __builtin_amdgcn_sched_barrier(0);
    buf = (buf == 2) ? 0 : buf + 1;
  }
#undef STAGE

#pragma unroll
  for (int i = 0; i < 4; ++i) {
#pragma unroll
    for (int j = 0; j < 4; ++j) {
      int col = n0 + wc * 64 + j * 16 + lr;
      float bi = bias[col];
      int rbase = m0 + wr * 64 + i * 16 + lg * 4;
      if (MODE == 2) {
        float* o = (float*)outp;
#pragma unroll
        for (int r = 0; r < 4; ++r) {
          size_t idx = (size_t)(rbase + r) * N + col;
          o[idx] = resid[idx] + acc[i][j][r] + bi;
        }
      } else if (MODE == 3) {
        u16* o = (u16*)outp;
#pragma unroll
        for (int r = 0; r < 4; ++r)
          o[(size_t)(rbase + r) * N + col] = f2bf(fmaxf(acc[i][j][r] + bi, 0.0f));
      } else {
        u16* qb = (u16*)outp;
        int which = col >> 10, nc = col & 1023;
        int hh = nc >> 6, dd = nc & 63;
        int bb = rbase >> 11, ss = rbase & 2047;
        if (which == 0) {
#pragma unroll
          for (int r = 0; r < 4; ++r)
            qb[((size_t)(bb * NH + hh) * SEQ + (ss + r)) * DKh + dd] = f2bf((acc[i][j][r] + bi) * qscale);
        } else {
          int4 p4 = *(const int4*)(pinv + bb * SEQ + ss);
          int pos[4] = {p4.x, p4.y, p4.z, p4.w};
          if (which == 1) {
            u16* kcb = qb + (size_t)(8u << 20);
#pragma unroll
            for (int r = 0; r < 4; ++r)
              if (pos[r] >= 0)
                kcb[((size_t)(bb * NH + hh) * SEQ + pos[r]) * DKh + dd] = f2bf(acc[i][j][r] + bi);
          } else {
            u16* vcb = qb + (size_t)2 * (8u << 20);
#pragma unroll
            for (int r = 0; r < 4; ++r)
              if (pos[r] >= 0) {
                int l = pos[r];
                int lo = l & 63;
                int pi = ((lo >> 4) & 1) * 32 + ((lo >> 2) & 3) * 8 + (lo >> 5) * 4 + (lo & 3);
                vcb[((size_t)(bb * NH + hh) * DKh + dd) * SEQ + (l & ~63) + pi] = f2bf(acc[i][j][r] + bi);
              }
          }
        }
      }
    }
  }
}

// ---- flash attention over COMPACTED kv: 512 thr (8 waves x 32 q-rows), KVBLK=128,
// gl16-staged double-buffer with COUNTED vmcnt (loads stay in flight across barriers).
__global__ __launch_bounds__(512) void attn_fwd(const u16* __restrict__ q,
                                                const u16* __restrict__ kc,
                                                const u16* __restrict__ vc,
                                                const int* __restrict__ lArr,
                                                const int* __restrict__ lpArr,
                                                const float* __restrict__ fbbc,
                                                u16* __restrict__ ctx) {
  __shared__ u16 lds[2][16384];
  int tid = threadIdx.x;
  int wid = tid >> 6, lane = tid & 63;
  int lr = lane & 15, lg = lane >> 4;
  int bh = blockIdx.x;
  int b = bh >> 4, hh = bh & 15;
  int q0 = blockIdx.y * 256 + wid * 32;
  const u16* qbase = q + (size_t)bh * SEQ * DKh;
  const u16* kcb = kc + (size_t)bh * SEQ * DKh;
  const u16* vcb = vc + (size_t)bh * DKh * SEQ;
  const float* fbbase = fbbc + b * SEQ;
  int Lb = lArr[b];
  int LP = lpArr[b];

  short8 qf[2][2];
#pragma unroll
  for (int i = 0; i < 2; ++i)
#pragma unroll
    for (int kk = 0; kk < 2; ++kk)
      qf[i][kk] = *(const short8*)(qbase + (size_t)(q0 + i * 16 + lr) * DKh + kk * 32 + lg * 8);

  int srow = tid >> 3;
  int schk = tid & 7;
  int ks0 = srow * 64 + ((schk ^ (srow & 7)) * 8);
  int vs0 = srow * SEQ + ((schk ^ (srow & 7)) * 8);
  int dst0 = tid * 8;

#define STAGE(B_, KV0) do { \
    gl16(kcb + (size_t)(KV0) * 64 + ks0, &lds[B_][dst0]); \
    gl16(kcb + (size_t)((KV0) + 64) * 64 + ks0, &lds[B_][dst0 + 4096]); \
    gl16(vcb + (size_t)(KV0) + vs0, &lds[B_][dst0 + 8192]); \
    gl16(vcb + (size_t)(KV0) + 64 + vs0, &lds[B_][dst0 + 12288]); \
  } while (0)

  int swzc = (lr & 7) << 3;

  f32x4 ot[2][4] = {};
  float mrow[2] = {-3e38f, -3e38f};
  float lsum[2] = {0.0f, 0.0f};

  STAGE(0, 0);
  asm volatile("s_waitcnt vmcnt(0)" ::: "memory");
  __builtin_amdgcn_s_barrier();

  int buf = 0;
  for (int kv0 = 0; kv0 < LP; kv0 += 128) {
    bool more = (kv0 + 128 < LP);
    if (more) STAGE(buf ^ 1, kv0 + 128);
    if (more) asm volatile("s_waitcnt vmcnt(4)" ::: "memory");
    else      asm volatile("s_waitcnt vmcnt(0)" ::: "memory");
    __builtin_amdgcn_s_barrier();

#pragma unroll
    for (int sB = 0; sB < 2; ++sB) {
      const u16* Ks = &lds[buf][sB * 4096];
      const u16* Vs = &lds[buf][8192 + sB * 4096];
      int kvs = kv0 + sB * 64;

      f32x4 st[2][4] = {};
      __builtin_amdgcn_s_setprio(1);
#pragma unroll
      for (int kk = 0; kk < 2; ++kk) {
        short8 kf[4];
#pragma unroll
        for (int j = 0; j < 4; ++j)
          kf[j] = *(const short8*)&Ks[(j * 16 + lr) * 64 + ((kk * 32 + lg * 8) ^ swzc)];
#pragma unroll
        for (int i = 0; i < 2; ++i)
#pragma unroll
          for (int j = 0; j < 4; ++j)
            st[i][j] = __builtin_amdgcn_mfma_f32_16x16x32_bf16(kf[j], qf[i][kk], st[i][j], 0, 0, 0);
      }
      __builtin_amdgcn_s_setprio(0);

      bool tail = (kvs + 64 > Lb);

      u32x4 pa[2][2];
#pragma unroll
      for (int i = 0; i < 2; ++i) {
        float p[4][4];
        if (tail) {
#pragma unroll
          for (int j = 0; j < 4; ++j) {
            float4 f4 = *(const float4*)(fbbase + kvs + j * 16 + lg * 4);
            p[j][0] = st[i][j][0] + f4.x;
            p[j][1] = st[i][j][1] + f4.y;
            p[j][2] = st[i][j][2] + f4.z;
            p[j][3] = st[i][j][3] + f4.w;
          }
        } else {
#pragma unroll
          for (int j = 0; j < 4; ++j)
#pragma unroll
            for (int r = 0; r < 4; ++r) p[j][r] = st[i][j][r];
        }
        float mx = -3e38f;
#pragma unroll
        for (int j = 0; j < 4; ++j)
#pragma unroll
          for (int r = 0; r < 4; ++r) mx = fmaxf(mx, p[j][r]);
        mx = fmaxf(mx, __shfl_xor(mx, 16));
        mx = fmaxf(mx, __shfl_xor(mx, 32));
        float mnew = fmaxf(mrow[i], mx);
        if (!__all(mnew - mrow[i] <= 8.0f)) {
          float corr = fexp2(mrow[i] - mnew);
          lsum[i] *= corr;
#pragma unroll
          for (int jd = 0; jd < 4; ++jd)
#pragma unroll
            for (int r = 0; r < 4; ++r) ot[i][jd][r] *= corr;
          mrow[i] = mnew;
        }
        float ps = 0.0f;
#pragma unroll
        for (int j = 0; j < 4; ++j)
#pragma unroll
          for (int r = 0; r < 4; ++r) {
            float pv = fexp2(p[j][r] - mrow[i]);
            p[j][r] = pv;
            ps += pv;
          }
        ps += __shfl_xor(ps, 16);
        ps += __shfl_xor(ps, 32);
        lsum[i] += ps;
#pragma unroll
        for (int ks = 0; ks < 2; ++ks) {
          pa[i][ks][0] = cvtpk(p[ks][0], p[ks][1]);
          pa[i][ks][1] = cvtpk(p[ks][2], p[ks][3]);
          pa[i][ks][2] = cvtpk(p[ks + 2][0], p[ks + 2][1]);
          pa[i][ks][3] = cvtpk(p[ks + 2][2], p[ks + 2][3]);
        }
      }

      __builtin_amdgcn_s_setprio(1);
#pragma unroll
      for (int ks = 0; ks < 2; ++ks) {
        short8 vf[4];
#pragma unroll
        for (int jd = 0; jd < 4; ++jd)
          vf[jd] = *(const short8*)&Vs[(jd * 16 + lr) * 64 + ((ks * 32 + lg * 8) ^ swzc)];
#pragma unroll
        for (int i = 0; i < 2; ++i)
#pragma unroll
          for (int jd = 0; jd < 4; ++jd)
            ot[i][jd] = __builtin_amdgcn_mfma_f32_16x16x32_bf16(vf[jd], *(short8*)&pa[i][ks], ot[i][jd], 0, 0, 0);
      }
      __builtin_amdgcn_s_setprio(0);
    }
    __builtin_amdgcn_s_barrier();
    buf ^= 1;
  }
#undef STAGE

  asm volatile("s_waitcnt vmcnt(0)" ::: "memory");
  __builtin_amdgcn_s_barrier();

  float inv0 = 1.0f / lsum[0], inv1 = 1.0f / lsum[1];
  u16* ep = &lds[0][wid * 2048];
#pragma unroll
  for (int i = 0; i < 2; ++i) {
    float inv = i ? inv1 : inv0;
#pragma unroll
    for (int jd = 0; jd < 4; ++jd) {
      uint32_t w0 = cvtpk(ot[i][jd][0] * inv, ot[i][jd][1] * inv);
      uint32_t w1 = cvtpk(ot[i][jd][2] * inv, ot[i][jd][3] * inv);
      uint32_t pk2[2] = {w0, w1};
      *(u16x4*)&ep[(i * 16 + lr) * 64 + ((jd * 16 + lg * 4) ^ swzc)] = *(u16x4*)pk2;
    }
  }
  __syncthreads();
  int q_ = lane >> 1;
  size_t orow = ((size_t)b * SEQ + q0 + q_) * DM + hh * DKh;
#pragma unroll
  for (int it = 0; it < 4; ++it) {
    int dc = (lane & 1) * 32 + it * 8;
    short8 vv = *(const short8*)&ep[q_ * 64 + (dc ^ ((q_ & 7) << 3))];
    *(short8*)(ctx + orow + dc) = vv;
  }
}

extern "C" void kernel_launch(void* const* d_in, const int* in_sizes, int n_in,
                              void* d_out, int out_size, void* d_ws, size_t ws_size,
                              hipStream_t stream) {
  const float* x   = (const float*)d_in[0];
  const int*   msk = (const int*)d_in[1];
  const float* wq  = (const float*)d_in[2];
  const float* bq  = (const float*)d_in[3];
  const float* wk  = (const float*)d_in[4];
  const float* bk  = (const float*)d_in[5];
  const float* wv  = (const float*)d_in[6];
  const float* bv  = (const float*)d_in[7];
  const float* wo  = (const float*)d_in[8];
  const float* bo  = (const float*)d_in[9];
  const float* w1  = (const float*)d_in[10];
  const float* b1  = (const float*)d_in[11];
  const float* w2  = (const float*)d_in[12];
  const float* b2  = (const float*)d_in[13];
  const float* a1  = (const float*)d_in[14];
  const float* be1 = (const float*)d_in[15];
  const float* a2  = (const float*)d_in[16];
  const float* be2 = (const float*)d_in[17];
  float* out = (float*)d_out;

  u16* wqT = (u16*)d_ws;
  u16* wkT = wqT + (1u << 20);
  u16* wvT = wkT + (1u << 20);
  u16* woT = wvT + (1u << 20);
  u16* w1T = woT + (1u << 20);
  u16* w2T = w1T + (4u << 20);
  u16* xn  = w2T + (4u << 20);
  u16* qb  = xn  + (8u << 20);
  u16* kb  = qb  + (8u << 20);     // compacted K [bh][l][64]
  u16* vtb = kb  + (8u << 20);     // compacted+permuted V^T [bh][d][*]
  u16* ctx = vtb + (8u << 20);
  u16* hb  = qb;                   // FFN hidden reuses qb..ctx (64 MB)
  float* bcat = (float*)ctx;       // QKV fused bias; ctx not live until attn
  int*   pinv = (int*)(ctx + (8u << 20));
  int*   lArr = pinv + NB * SEQ;
  int*   lpArr = lArr + 16;
  float* fbbc = (float*)(lpArr + 16);

  (void)hipFuncSetAttribute((const void*)gemm_v2<0>, hipFuncAttributeMaxDynamicSharedMemorySize, 72 * 1024);
  (void)hipFuncSetAttribute((const void*)gemm_v2<2>, hipFuncAttributeMaxDynamicSharedMemorySize, 72 * 1024);
  (void)hipFuncSetAttribute((const void*)gemm_v2<3>, hipFuncAttributeMaxDynamicSharedMemorySize, 72 * 1024);

  dim3 tb(32, 8);
  prep<<<12300, tb, 0, stream>>>(wq, wk, wv, wo, w1, w2, wqT, wkT, wvT, woT, w1T, w2T, bq, bk, bv, bcat);
  compact_idx<<<NB, 1024, 0, stream>>>(msk, pinv, lArr, lpArr, fbbc);

  ln_bf16<<<NB * SEQ, 256, 0, stream>>>(x, xn, a1, be1);

  // fused QKV: N=3072, 256x128 tiles -> grid 768
  gemm_v2<0><<<768, 512, 72 * 1024, stream>>>(xn, wqT, bcat, nullptr, qb, pinv, NB * SEQ, 3 * DM, DM, 0.125f * LOG2E);

  attn_fwd<<<dim3(NB * NH, SEQ / 256), 512, 0, stream>>>(qb, kb, vtb, lArr, lpArr, fbbc, ctx);

  // O-proj + residual: grid 256
  gemm_v2<2><<<256, 512, 72 * 1024, stream>>>(ctx, woT, bo, x, out, nullptr, NB * SEQ, DM, DM, 1.0f);

  ln_bf16<<<NB * SEQ, 256, 0, stream>>>(out, xn, a2, be2);

  // FFN1: N=4096 -> grid 1024
  gemm_v2<3><<<1024, 512, 72 * 1024, stream>>>(xn, w1T, b1, nullptr, hb, nullptr, NB * SEQ, DFF, DM, 1.0f);

  // FFN2 + residual: K=4096, grid 256
  gemm_v2<2><<<256, 512, 72 * 1024, stream>>>(hb, w2T, b2, out, out, nullptr, NB * SEQ, DM, DFF, 1.0f);
}